// Round 1
// baseline (411.445 us; speedup 1.0000x reference)
//
#include <hip/hip_runtime.h>

#define NJ 24
#define NV 6890
#define NB 1024
#define KK 220          // 207 pose + 10 betas + 1 template + 2 zero pad
#define VT 8            // verts per block in k2
#define JTR_OFF (NB*NV*3)

__constant__ int c_par[NJ] = {-1,0,0,0,1,2,3,4,5,6,7,8,9,9,9,12,13,14,16,17,18,19,20,21};

// ---------------------------------------------------------------------------
// k0: fold joint regressor:  Jc[j][c][s] , s<10: Jreg@shapedirs, s=10: Jreg@tmpl
// grid (24,4) x 256, atomicAdd partials (Jc memset to 0 first)
// ---------------------------------------------------------------------------
__global__ void k0(const float* __restrict__ Jreg, const float* __restrict__ vtempl,
                   const float* __restrict__ shdirs, float* __restrict__ Jc)
{
    int j = blockIdx.x;
    float acc[33];
#pragma unroll
    for (int i = 0; i < 33; ++i) acc[i] = 0.0f;

    for (int v = blockIdx.y * 256 + threadIdx.x; v < NV; v += 1024) {
        float r = Jreg[j * NV + v];
#pragma unroll
        for (int c = 0; c < 3; ++c) {
            acc[c * 11 + 10] += r * vtempl[v * 3 + c];
            const float* sd = &shdirs[(v * 3 + c) * 10];
#pragma unroll
            for (int s = 0; s < 10; ++s) acc[c * 11 + s] += r * sd[s];
        }
    }
    // wave reduce (64 lanes)
#pragma unroll
    for (int i = 0; i < 33; ++i) {
        float x = acc[i];
        for (int o = 32; o > 0; o >>= 1) x += __shfl_down(x, o, 64);
        acc[i] = x;
    }
    __shared__ float red[4][33];
    int w = threadIdx.x >> 6, l = threadIdx.x & 63;
    if (l == 0) {
#pragma unroll
        for (int i = 0; i < 33; ++i) red[w][i] = acc[i];
    }
    __syncthreads();
    if (threadIdx.x < 33) {
        float s = red[0][threadIdx.x] + red[1][threadIdx.x] +
                  red[2][threadIdx.x] + red[3][threadIdx.x];
        atomicAdd(&Jc[j * 33 + threadIdx.x], s);
    }
}

// ---------------------------------------------------------------------------
// k1: per-batch: Rodrigues, A rows (pose_map|betas|1|0), th_j, kinematic chain,
//     G2 (t-corrected), th_jtr output.  One wave per batch, 4 batches/block.
// A4 layout:  float idx (k>>2)*4096 + b*4 + (k&3)   (float4 per (k4,b))
// G4 layout:  float idx ((j*3+m)*NB + b)*4 + n      (row m of joint j as float4)
// ---------------------------------------------------------------------------
__global__ void k1(const float* __restrict__ pose, const float* __restrict__ betas,
                   const float* __restrict__ trans, const float* __restrict__ Jc,
                   float* __restrict__ A4, float* __restrict__ G4,
                   float* __restrict__ out)
{
    __shared__ float rots[4][NJ][9];
    __shared__ float thj [4][NJ][3];
    __shared__ float res [4][NJ][16];

    int w = threadIdx.x >> 6;
    int l = threadIdx.x & 63;
    int b = blockIdx.x * 4 + w;

    if (l < NJ) {
        int j = l;
        float ax = pose[b * 72 + j * 3 + 0];
        float ay = pose[b * 72 + j * 3 + 1];
        float az = pose[b * 72 + j * 3 + 2];
        float theta = sqrtf(ax * ax + ay * ay + az * az + 1e-8f);
        float inv = 1.0f / theta;
        float kx = ax * inv, ky = ay * inv, kz = az * inv;
        float c = cosf(theta), s = sinf(theta), mc = 1.0f - c;
        float R[9];
        R[0] = 1.0f - mc * (ky * ky + kz * kz);
        R[1] = -s * kz + mc * (kx * ky);
        R[2] =  s * ky + mc * (kx * kz);
        R[3] =  s * kz + mc * (kx * ky);
        R[4] = 1.0f - mc * (kx * kx + kz * kz);
        R[5] = -s * kx + mc * (ky * kz);
        R[6] = -s * ky + mc * (kx * kz);
        R[7] =  s * kx + mc * (ky * kz);
        R[8] = 1.0f - mc * (kx * kx + ky * ky);
#pragma unroll
        for (int e = 0; e < 9; ++e) rots[w][j][e] = R[e];
        if (j >= 1) {
            int base = (j - 1) * 9;
#pragma unroll
            for (int e = 0; e < 9; ++e) {
                int k = base + e;
                float val = R[e] - ((e == 0 || e == 4 || e == 8) ? 1.0f : 0.0f);
                A4[(k >> 2) * 4096 + b * 4 + (k & 3)] = val;
            }
        }
#pragma unroll
        for (int c3 = 0; c3 < 3; ++c3) {
            float acc = Jc[(j * 3 + c3) * 11 + 10];
#pragma unroll
            for (int s10 = 0; s10 < 10; ++s10)
                acc += Jc[(j * 3 + c3) * 11 + s10] * betas[b * 10 + s10];
            thj[w][j][c3] = acc;
        }
    } else if (l < 37) {
        int k; float val;
        if (l < 34)      { k = 207 + (l - 24); val = betas[b * 10 + (l - 24)]; }
        else if (l == 34){ k = 217; val = 1.0f; }
        else             { k = 218 + (l - 35); val = 0.0f; }
        A4[(k >> 2) * 4096 + b * 4 + (k & 3)] = val;
    }
    __syncthreads();

    // chain: res[0] = make44(rots[0], thj[0]); res[i] = res[parent] @ rel_i
    if (l < 16) {
        int m = l >> 2, n = l & 3;
        float v;
        if (m < 3) v = (n < 3) ? rots[w][0][m * 3 + n] : thj[w][0][m];
        else       v = (n == 3) ? 1.0f : 0.0f;
        res[w][0][l] = v;
    }
    __syncthreads();
#pragma unroll
    for (int i = 1; i < NJ; ++i) {
        int p = c_par[i];
        if (l < 16) {
            int m = l >> 2, n = l & 3;
            float acc = 0.0f;
#pragma unroll
            for (int k3 = 0; k3 < 3; ++k3) {
                float relkn = (n < 3) ? rots[w][i][k3 * 3 + n]
                                      : (thj[w][i][k3] - thj[w][p][k3]);
                acc += res[w][p][m * 4 + k3] * relkn;
            }
            if (n == 3) acc += res[w][p][m * 4 + 3];
            res[w][i][l] = acc;
        }
        __syncthreads();
    }

    // th_jtr = G[:, :, :3, 3] + trans
    if (l < NJ) {
        int j = l;
#pragma unroll
        for (int c3 = 0; c3 < 3; ++c3)
            out[JTR_OFF + b * 72 + j * 3 + c3] = res[w][j][c3 * 4 + 3] + trans[b * 3 + c3];
    }
    // G2: cols 0..2 = G, col 3 = G.t - G.R @ thj
    for (int k = l; k < 288; k += 64) {
        int j = k / 12, m = (k % 12) >> 2, n = k & 3;
        float v;
        if (n < 3) v = res[w][j][m * 4 + n];
        else v = res[w][j][m * 4 + 3] - (res[w][j][m * 4 + 0] * thj[w][j][0] +
                                         res[w][j][m * 4 + 1] * thj[w][j][1] +
                                         res[w][j][m * 4 + 2] * thj[w][j][2]);
        G4[((j * 3 + m) * NB + b) * 4 + n] = v;
    }
}

// ---------------------------------------------------------------------------
// k2: fused pose-GEMM + blend.  Block = 256 threads = all 1024 batches (4 each),
// VT=8 verts staged in LDS as unified K=220 rows [posedirs|shapedirs|tmpl|0,0].
// ---------------------------------------------------------------------------
__launch_bounds__(256, 3)
__global__ void k2(const float* __restrict__ pdirs, const float* __restrict__ shdirs,
                   const float* __restrict__ vtempl, const float* __restrict__ wts,
                   const float* __restrict__ A4, const float* __restrict__ G4,
                   const float* __restrict__ trans, float* __restrict__ out)
{
    __shared__ float pd[VT * 3 * KK];   // 21.1 KB
    __shared__ float wl[VT][NJ];

    int tid = threadIdx.x;
    int v0 = blockIdx.x * VT;

    for (int i = tid; i < VT * 3 * KK; i += 256) {
        int vt = i / (3 * KK);
        int rem = i - vt * (3 * KK);
        int c = rem / KK;
        int k = rem - c * KK;
        int v = v0 + vt;
        float val = 0.0f;
        if (v < NV) {
            if (k < 207)      val = pdirs[(v * 3 + c) * 207 + k];
            else if (k < 217) val = shdirs[(v * 3 + c) * 10 + (k - 207)];
            else if (k == 217) val = vtempl[v * 3 + c];
        }
        pd[i] = val;
    }
    for (int i = tid; i < VT * NJ; i += 256) {
        int vt = i / NJ, j = i - vt * NJ;
        wl[vt][j] = (v0 + vt < NV) ? wts[(v0 + vt) * NJ + j] : 0.0f;
    }
    __syncthreads();

    float vp[VT][3][4];
#pragma unroll
    for (int vt = 0; vt < VT; ++vt)
#pragma unroll
        for (int c = 0; c < 3; ++c)
#pragma unroll
            for (int mb = 0; mb < 4; ++mb) vp[vt][c][mb] = 0.0f;

    const float4* A4v = (const float4*)A4;
    for (int k4 = 0; k4 < KK; k4 += 4) {
        float4 a[4];
#pragma unroll
        for (int mb = 0; mb < 4; ++mb) a[mb] = A4v[(k4 >> 2) * 1024 + tid + mb * 256];
#pragma unroll
        for (int vt = 0; vt < VT; ++vt)
#pragma unroll
            for (int c = 0; c < 3; ++c) {
                float4 p4 = *(const float4*)&pd[(vt * 3 + c) * KK + k4];
#pragma unroll
                for (int mb = 0; mb < 4; ++mb)
                    vp[vt][c][mb] += p4.x * a[mb].x + p4.y * a[mb].y +
                                     p4.z * a[mb].z + p4.w * a[mb].w;
            }
    }

    const float4* G4v = (const float4*)G4;
#pragma unroll 1
    for (int mb = 0; mb < 4; ++mb) {
        int b = tid + mb * 256;
        float vert[VT][3];
#pragma unroll
        for (int vt = 0; vt < VT; ++vt) {
            vert[vt][0] = 0.0f; vert[vt][1] = 0.0f; vert[vt][2] = 0.0f;
        }
        for (int j = 0; j < NJ; ++j) {
            float4 g0 = G4v[(j * 3 + 0) * NB + b];
            float4 g1 = G4v[(j * 3 + 1) * NB + b];
            float4 g2 = G4v[(j * 3 + 2) * NB + b];
#pragma unroll
            for (int vt = 0; vt < VT; ++vt) {
                float w = wl[vt][j];
                float x = vp[vt][0][mb], y = vp[vt][1][mb], z = vp[vt][2][mb];
                vert[vt][0] += w * (g0.x * x + g0.y * y + g0.z * z + g0.w);
                vert[vt][1] += w * (g1.x * x + g1.y * y + g1.z * z + g1.w);
                vert[vt][2] += w * (g2.x * x + g2.y * y + g2.z * z + g2.w);
            }
        }
        float tx = trans[b * 3 + 0], ty = trans[b * 3 + 1], tz = trans[b * 3 + 2];
#pragma unroll
        for (int vt = 0; vt < VT; ++vt) {
            int v = v0 + vt;
            if (v < NV) {
                out[b * (NV * 3) + v * 3 + 0] = vert[vt][0] + tx;
                out[b * (NV * 3) + v * 3 + 1] = vert[vt][1] + ty;
                out[b * (NV * 3) + v * 3 + 2] = vert[vt][2] + tz;
            }
        }
    }
}

extern "C" void kernel_launch(void* const* d_in, const int* in_sizes, int n_in,
                              void* d_out, int out_size, void* d_ws, size_t ws_size,
                              hipStream_t stream)
{
    const float* pose   = (const float*)d_in[0];
    const float* betas  = (const float*)d_in[1];
    const float* trans  = (const float*)d_in[2];
    const float* vtempl = (const float*)d_in[3];
    const float* shdirs = (const float*)d_in[4];
    const float* pdirs  = (const float*)d_in[5];
    const float* Jreg   = (const float*)d_in[6];
    const float* wts    = (const float*)d_in[7];
    float* out = (float*)d_out;
    float* ws  = (float*)d_ws;

    float* Jc = ws;                 // 792 floats
    float* A4 = ws + 1024;          // 220*1024 = 225280 floats
    float* G4 = ws + 226304;        // 288*1024 = 294912 floats

    hipMemsetAsync(Jc, 0, NJ * 33 * sizeof(float), stream);
    hipLaunchKernelGGL(k0, dim3(NJ, 4), dim3(256), 0, stream, Jreg, vtempl, shdirs, Jc);
    hipLaunchKernelGGL(k1, dim3(NB / 4), dim3(256), 0, stream,
                       pose, betas, trans, Jc, A4, G4, out);
    hipLaunchKernelGGL(k2, dim3((NV + VT - 1) / VT), dim3(256), 0, stream,
                       pdirs, shdirs, vtempl, wts, A4, G4, trans, out);
}